// Round 9
// baseline (132.552 us; speedup 1.0000x reference)
//
#include <hip/hip_runtime.h>

#define N_IMG    1024
#define N_VIEWS  90
#define CENTER   512
#define NTHREADS 512
#define NWAVES   8
#define JOBS     4          // 4 jobs of 64x64 per block = 256-row y-quarter
#define PIT      96         // unified LDS pitch; PIT % 32 == 0 -> bank = x0 % 32
#define BUFW     9088       // 92 rows * 96 + 256 (16B-DMA tail overshoot); 35.5 KB -> 4 blk/CU

typedef float v2f __attribute__((ext_vector_type(2)));

// Effective map (post-fold params c,s,cx,cy):
//   x = s*Y + fmaf(c, X, cx),  y = c*Y + fmaf(-s, X, cy)
// Fold (|s0|>|c0|): (c,s,cx,cy,src) <- (s0, -c0, 1023-cy0, cx0, T) with
// T[j][i] = img[1023-i][j]. Identity is EXACT incl. cval=0 borders:
// T_cont(y_T,x_T) = img_cont(1023-x_T, y_T) = img_cont(y_in, x_in).
// Post-fold |c| >= 0.707 for every angle -> one staging/sampling path,
// pitch 96 (bank = x0 mod 32, per-lane stride |c| in [0.707,1]) -> reads at
// the 2-way structural floor (R8-verified: 6.17M ~= 2 sub-accesses/ds_read2).
__device__ __forceinline__ void map_coords(float ca, float sa, float cx, float cy,
                                           float Xf, float Yf,
                                           float& x_in, float& y_in) {
    const float fx0 = fmaf(ca, Xf, cx);
    const float fy0 = fmaf(-sa, Xf, cy);
    x_in = fmaf(sa, Yf, fx0);
    y_in = fmaf(ca, Yf, fy0);
}

__device__ __forceinline__ void gload_lds4(const float* g, float* l) {
    __builtin_amdgcn_global_load_lds((const __attribute__((address_space(1))) void*)g,
                                     (__attribute__((address_space(3))) void*)l, 4, 0, 0);
}
__device__ __forceinline__ void gload_lds16(const float* g, float* l) {
    __builtin_amdgcn_global_load_lds((const __attribute__((address_space(1))) void*)g,
                                     (__attribute__((address_space(3))) void*)l, 16, 0, 0);
}

// transposed-flip copy: T[j][i] = img[1023-i][j]; 256 blocks x 256 thr,
// 64x64 tiles via LDS (65 pitch), coalesced on both sides.
__global__ __launch_bounds__(256) void transpose_flip(const float* __restrict__ img,
                                                      float* __restrict__ T) {
    __shared__ float tile[64][65];
    const int t  = blockIdx.x, tr = t >> 4, tc = t & 15;
    const int tid = threadIdx.x, lane = tid & 63, w = tid >> 6;   // 4 waves
    #pragma unroll
    for (int k = 0; k < 16; ++k) {
        const int row = (w << 4) + k;
        tile[row][lane] = img[(size_t)((tr << 6) + row) * N_IMG + (tc << 6) + lane];
    }
    __syncthreads();
    #pragma unroll
    for (int k = 0; k < 16; ++k) {
        const int j = (tc << 6) + (w << 4) + k;       // img col -> T row
        const int i = 1023 - ((tr << 6) + lane);      // img row r -> T col 1023-r
        T[(size_t)j * N_IMG + i] = tile[lane][(w << 4) + k];
    }
}

// One block = (angle, 64-col x-tile, 256-row y-quarter): 4 sequential 64x64
// jobs (R8-verified engine). Round 9 change: the sampler is restructured for
// LDS memory-level parallelism — per batch of 4 samples, all 4 indices are
// computed first, all 8 ds_read2 issue back-to-back, weights are computed
// while the loads are in flight, then the packed interpolation runs.
// Identical arithmetic and accumulation order to R8 (bit-identical output);
// the point is to spend the 64-VGPR budget (launch_bounds 512,8) on live
// load results instead of serializing issue->wait->use at 24 VGPRs.
__global__ __launch_bounds__(NTHREADS, 8) void radon_fused(const float* __restrict__ img,
                                                           const float* __restrict__ Tbuf,
                                                           const float* __restrict__ theta,
                                                           float* __restrict__ out,
                                                           int useT) {
    __shared__ float buf[BUFW];          // 35.5 KB -> 4 blocks/CU

    const int tx = blockIdx.x;
    const int q  = blockIdx.y;
    const int a  = blockIdx.z;
    const int X0 = tx * 64;
    const int Yq = q * (JOBS * 64);      // 0,256,512,768
    const int tid  = threadIdx.x;
    const int lane = tid & 63;
    const int wv   = tid >> 6;           // 0..7

    // ---- per-angle params; double sincos once per block (numeric margin) ----
    const float ang = theta[a] * 0.017453292519943295f;
    double sd_, cd_;
    sincos((double)ang, &sd_, &cd_);
    const float s0 = (float)sd_, c0 = (float)cd_;
    const float cx0 = (float)CENTER * (1.0f - c0 - s0);
    const float cy0 = (float)CENTER * (1.0f - c0 + s0);

    float c, s, cx, cy;
    const float* __restrict__ src;
    if (useT && fabsf(s0) > fabsf(c0)) {      // fold steep -> |c| >= 0.707
        c = s0; s = -c0; cx = 1023.0f - cy0; cy = cx0; src = Tbuf;
    } else {
        c = c0; s = s0;  cx = cx0;            cy = cy0;  src = img;
    }

    // ---- per-lane job params: lane (mod 4) owns job jj ----
    const int jj = lane & (JOBS - 1);
    const float Yb = (float)(Yq + jj * 64);
    float x00, y00, x01, y01, x10, y10, x11, y11;
    map_coords(c, s, cx, cy, (float)X0,        Yb,        x00, y00);
    map_coords(c, s, cx, cy, (float)(X0 + 63), Yb,        x01, y01);
    map_coords(c, s, cx, cy, (float)X0,        Yb + 63.f, x10, y10);
    map_coords(c, s, cx, cy, (float)(X0 + 63), Yb + 63.f, x11, y11);
    const float xmin = fminf(fminf(x00, x01), fminf(x10, x11));
    const float xmax = fmaxf(fmaxf(x00, x01), fmaxf(x10, x11));
    const float ymin = fminf(fminf(y00, y01), fminf(y10, y11));
    const float ymax = fmaxf(fmaxf(y00, y01), fmaxf(y10, y11));

    const int ix0 = (int)floorf(xmin);
    const int ix1 = (int)floorf(xmax) + 1;   // rightmost tap; ix1-ix0 <= 91
    const int iy0 = (int)floorf(ymin);
    const int iy1 = (int)floorf(ymax) + 1;   // bottom tap;   iy1-iy0 <= 91

    const bool empty = (ix1 < 0) || (ix0 > N_IMG - 1) ||
                       (iy1 < 0) || (iy0 > N_IMG - 1);
    const bool interior = (ix0 >= 0) && (ix1 <= N_IMG - 1) &&
                          (iy0 >= 0) && (iy1 <= N_IMG - 1);
    // window: 4-aligned, 96 wide, covers [ix0, ix1] (ix1-win <= 91+3 <= 94)
    const int winl = interior ? min(ix0 & ~3, N_IMG - PIT) : (ix0 & ~3);
    const int nrl  = iy1 - iy0 + 1;          // staged rows <= 92
    const int iy0l = iy0;
    const int fll  = empty ? 1 : (interior ? 2 : 0);

    // ---- per-lane sample-line constants (lane = output column) ----
    const float Xf  = (float)(X0 + lane);
    const float bx  = fmaf(c, Xf, cx);       // x = s*Y + bx
    const float by  = fmaf(-s, Xf, cy);      // y = c*Y + by
    const v2f s2 = {s, s}, c2 = {c, c};
    const v2f bx2 = {bx, bx}, by2 = {by, by};
    const v2f P2 = {(float)PIT, (float)PIT};
    float acc = 0.0f;

    for (int j = 0; j < JOBS; ++j) {
        const int win   = __shfl(winl, j);
        const int iyj   = __shfl(iy0l, j);
        const int nrows = __shfl(nrl,  j);
        const int fl    = __shfl(fll,  j);
        if (fl == 1) continue;               // block-uniform: skip empty job

        if (fl & 2) {
            // interior: ONE contiguous region copy (pitch == staged width)
            const int D = nrows * PIT;
            for (int o = wv * 256; o < D; o += NWAVES * 256) {
                const int d = o + 4 * lane;
                const int r = (unsigned)d / 96u;
                const int cc = d - r * 96;
                const int gr = min(iyj + r, N_IMG - 1);   // tail overshoot clamp
                gload_lds16(src + (size_t)gr * N_IMG + win + cc, buf + o);
            }
        } else {
            // border: masked per-lane DMA; off-image words -> ds_write 0
            for (int r = wv; r < nrows; r += NWAVES) {
                const int gy = iyj + r;
                const bool rok = ((unsigned)gy < (unsigned)N_IMG);
                const float* gp = src + (size_t)gy * N_IMG;
                float* l = buf + r * PIT;
                const int gx = win + lane;
                if (rok && (unsigned)gx < (unsigned)N_IMG) gload_lds4(gp + gx, l);
                else l[lane] = 0.0f;
                if (lane < 32) {
                    const int gx2 = gx + 64;
                    if (rok && (unsigned)gx2 < (unsigned)N_IMG) gload_lds4(gp + gx2, l + 64);
                    else l[64 + lane] = 0.0f;
                }
            }
        }
        __syncthreads();     // drains this block's DMA; staging visible

        // ---- sample 8 dst rows (wave wv -> rows j*64 + wv*8 ..+8) ----
        // two batches of 4 samples; per batch: indices -> 8 ds_read2 issued
        // together -> weights under the loads -> packed bilinear.
        const float Yw = (float)(Yq + j * 64 + wv * 8);
        const float basef = -(float)(iyj * PIT + win);
        const v2f b2 = {basef, basef};
        v2f acc2 = {0.0f, 0.0f};
        #pragma unroll
        for (int half = 0; half < 2; ++half) {
            const float Yh = Yw + (float)(half << 2);
            const v2f Y2a = {Yh,        Yh + 1.0f};
            const v2f Y2b = {Yh + 2.0f, Yh + 3.0f};
            // coords + integer indices for all 4 samples (driftless exact)
            const v2f x2a = s2 * Y2a + bx2;      // v_pk_fma
            const v2f y2a = c2 * Y2a + by2;
            const v2f x2b = s2 * Y2b + bx2;
            const v2f y2b = c2 * Y2b + by2;
            const v2f x0a = {floorf(x2a.x), floorf(x2a.y)};
            const v2f y0a = {floorf(y2a.x), floorf(y2a.y)};
            const v2f x0b = {floorf(x2b.x), floorf(x2b.y)};
            const v2f y0b = {floorf(y2b.x), floorf(y2b.y)};
            const v2f lifa = y0a * P2 + x0a + b2;    // exact (< 2^23)
            const v2f lifb = y0b * P2 + x0b + b2;
            const int li0 = (int)lifa.x;
            const int li1 = (int)lifa.y;
            const int li2 = (int)lifb.x;
            const int li3 = (int)lifb.y;
            // 8 ds_read2_b32 issued back-to-back (pairs (li,li+1) merge)
            const v2f t00a = {buf[li0],           buf[li1]};
            const v2f t01a = {buf[li0 + 1],       buf[li1 + 1]};
            const v2f t10a = {buf[li0 + PIT],     buf[li1 + PIT]};
            const v2f t11a = {buf[li0 + PIT + 1], buf[li1 + PIT + 1]};
            const v2f t00b = {buf[li2],           buf[li3]};
            const v2f t01b = {buf[li2 + 1],       buf[li3 + 1]};
            const v2f t10b = {buf[li2 + PIT],     buf[li3 + PIT]};
            const v2f t11b = {buf[li2 + PIT + 1], buf[li3 + PIT + 1]};
            // weights computed while the loads are in flight
            const v2f wxa = x2a - x0a, wya = y2a - y0a;
            const v2f wxb = x2b - x0b, wyb = y2b - y0b;
            // packed bilinear, same op/accumulation order as R8
            const v2f topa = (t01a - t00a) * wxa + t00a;
            const v2f bota = (t11a - t10a) * wxa + t10a;
            acc2 += (bota - topa) * wya + topa;
            const v2f topb = (t01b - t00b) * wxb + t00b;
            const v2f botb = (t11b - t10b) * wxb + t10b;
            acc2 += (botb - topb) * wyb + topb;
        }
        acc += acc2.x + acc2.y;

        __syncthreads();     // all waves done reading before next staging
    }

    // ---- block reduce (overlay buf) + atomic merge of 4 y-quarters ----
    buf[wv * 64 + lane] = acc;
    __syncthreads();
    if (wv == 0) {
        float ssum = 0.0f;
        #pragma unroll
        for (int w = 0; w < NWAVES; ++w) ssum += buf[w * 64 + lane];
        atomicAdd(&out[(size_t)(X0 + lane) * N_VIEWS + a], ssum);
    }
}

extern "C" void kernel_launch(void* const* d_in, const int* in_sizes, int n_in,
                              void* d_out, int out_size, void* d_ws, size_t ws_size,
                              hipStream_t stream) {
    const float* img   = (const float*)d_in[0];   // [1024, 1024] f32
    const float* theta = (const float*)d_in[1];   // [90] f32 degrees
    float* out = (float*)d_out;                   // [1024, 90] f32

    float* T = (float*)d_ws;                      // 4 MB transposed-flip copy
    const int useT = (ws_size >= (size_t)N_IMG * N_IMG * sizeof(float)) ? 1 : 0;

    (void)hipMemsetAsync(d_out, 0, (size_t)out_size * sizeof(float), stream);
    if (useT)
        transpose_flip<<<dim3(256), 256, 0, stream>>>(img, T);
    radon_fused<<<dim3(16, 4, N_VIEWS), NTHREADS, 0, stream>>>(img, useT ? T : img,
                                                               theta, out, useT);
}

// Round 10
// 128.143 us; speedup vs baseline: 1.0344x; 1.0344x over previous
//
#include <hip/hip_runtime.h>

#define N_IMG    1024
#define N_VIEWS  90
#define CENTER   512
#define NTHREADS 512
#define NWAVES   8
#define JOBS     4          // 4 jobs of 64x64 per block = 256-row y-quarter
#define PIT      96         // unified LDS pitch; PIT % 32 == 0 -> bank = x0 % 32
#define BUFW     9088       // 92 rows * 96 + 256 (16B-DMA tail overshoot); 35.5 KB -> 4 blk/CU

typedef float v2f __attribute__((ext_vector_type(2)));

// Effective map (post-fold params c,s,cx,cy):
//   x = s*Y + fmaf(c, X, cx),  y = c*Y + fmaf(-s, X, cy)
// Fold (|s0|>|c0|): (c,s,cx,cy,src) <- (s0, -c0, 1023-cy0, cx0, T) with
// T[j][i] = img[1023-i][j]. Identity is EXACT incl. cval=0 borders.
// Post-fold |c| >= 0.707 for every angle -> one staging/sampling path,
// pitch 96 (bank = x0 mod 32, per-lane stride |c| in [0.707,1]) -> reads at
// the 2-way structural floor (R8-verified: 6.17M ~= 2 sub-accesses/ds_read2).
__device__ __forceinline__ void map_coords(float ca, float sa, float cx, float cy,
                                           float Xf, float Yf,
                                           float& x_in, float& y_in) {
    const float fx0 = fmaf(ca, Xf, cx);
    const float fy0 = fmaf(-sa, Xf, cy);
    x_in = fmaf(sa, Yf, fx0);
    y_in = fmaf(ca, Yf, fy0);
}

__device__ __forceinline__ void gload_lds4(const float* g, float* l) {
    __builtin_amdgcn_global_load_lds((const __attribute__((address_space(1))) void*)g,
                                     (__attribute__((address_space(3))) void*)l, 4, 0, 0);
}
__device__ __forceinline__ void gload_lds16(const float* g, float* l) {
    __builtin_amdgcn_global_load_lds((const __attribute__((address_space(1))) void*)g,
                                     (__attribute__((address_space(3))) void*)l, 16, 0, 0);
}

// Combined prep dispatch: blocks 0..255 do the transposed-flip copy
// T[j][i] = img[1023-i][j] (64x64 LDS tiles, coalesced both sides);
// block 256 computes the 90 per-angle parameter records once (f64 sincos,
// then the SAME f32 cx/cy arithmetic as the R8 in-kernel version):
//   prm[a*8 +0..4] = c, s, cx, cy, foldFlag
__global__ __launch_bounds__(256) void prep(const float* __restrict__ img,
                                            float* __restrict__ T,
                                            const float* __restrict__ theta,
                                            float* __restrict__ prm) {
    if (blockIdx.x == 256) {
        const int a = threadIdx.x;
        if (a < N_VIEWS) {
            const float ang = theta[a] * 0.017453292519943295f;
            double sd_, cd_;
            sincos((double)ang, &sd_, &cd_);
            const float s0 = (float)sd_, c0 = (float)cd_;
            const float cx0 = (float)CENTER * (1.0f - c0 - s0);
            const float cy0 = (float)CENTER * (1.0f - c0 + s0);
            float c, s, cx, cy, fl;
            if (fabsf(s0) > fabsf(c0)) {       // fold steep -> |c| >= 0.707
                c = s0; s = -c0; cx = 1023.0f - cy0; cy = cx0; fl = 1.0f;
            } else {
                c = c0; s = s0;  cx = cx0;            cy = cy0;  fl = 0.0f;
            }
            float* p = prm + (a << 3);
            p[0] = c; p[1] = s; p[2] = cx; p[3] = cy; p[4] = fl;
        }
        return;
    }
    __shared__ float tile[64][65];
    const int t  = blockIdx.x, tr = t >> 4, tc = t & 15;
    const int tid = threadIdx.x, lane = tid & 63, w = tid >> 6;   // 4 waves
    #pragma unroll
    for (int k = 0; k < 16; ++k) {
        const int row = (w << 4) + k;
        tile[row][lane] = img[(size_t)((tr << 6) + row) * N_IMG + (tc << 6) + lane];
    }
    __syncthreads();
    #pragma unroll
    for (int k = 0; k < 16; ++k) {
        const int j = (tc << 6) + (w << 4) + k;       // img col -> T row
        const int i = 1023 - ((tr << 6) + lane);      // img row r -> T col 1023-r
        T[(size_t)j * N_IMG + i] = tile[lane][(w << 4) + k];
    }
}

// One block = (angle, 64-col x-tile, 256-row y-quarter): 4 sequential 64x64
// jobs — the R8-verified engine. Round-10 changes only: (1) per-angle params
// are scalar-loaded from the precomputed table (no per-block f64 sincos);
// (2) s_setprio(1) around the sample phase (T5 — role diversity exists
// across the 4 co-resident blocks: sampling waves vs staging/draining waves).
__global__ __launch_bounds__(NTHREADS, 8) void radon_fused(const float* __restrict__ img,
                                                           const float* __restrict__ Tbuf,
                                                           const float* __restrict__ theta,
                                                           const float* __restrict__ prm,
                                                           float* __restrict__ out,
                                                           int useT) {
    __shared__ float buf[BUFW];          // 35.5 KB -> 4 blocks/CU

    const int tx = blockIdx.x;
    const int q  = blockIdx.y;
    const int a  = blockIdx.z;
    const int X0 = tx * 64;
    const int Yq = q * (JOBS * 64);      // 0,256,512,768
    const int tid  = threadIdx.x;
    const int lane = tid & 63;
    const int wv   = tid >> 6;           // 0..7

    // ---- per-angle params: scalar loads from table (fallback: f32 sincos) ----
    float c, s, cx, cy;
    const float* __restrict__ src;
    if (useT) {
        const float* p = prm + (a << 3);
        c = p[0]; s = p[1]; cx = p[2]; cy = p[3];
        src = (p[4] != 0.0f) ? Tbuf : img;
    } else {
        float s0, c0;
        __sincosf(theta[a] * 0.017453292519943295f, &s0, &c0);
        c = c0; s = s0;
        cx = (float)CENTER * (1.0f - c0 - s0);
        cy = (float)CENTER * (1.0f - c0 + s0);
        src = img;
    }

    // ---- per-lane job params: lane (mod 4) owns job jj ----
    const int jj = lane & (JOBS - 1);
    const float Yb = (float)(Yq + jj * 64);
    float x00, y00, x01, y01, x10, y10, x11, y11;
    map_coords(c, s, cx, cy, (float)X0,        Yb,        x00, y00);
    map_coords(c, s, cx, cy, (float)(X0 + 63), Yb,        x01, y01);
    map_coords(c, s, cx, cy, (float)X0,        Yb + 63.f, x10, y10);
    map_coords(c, s, cx, cy, (float)(X0 + 63), Yb + 63.f, x11, y11);
    const float xmin = fminf(fminf(x00, x01), fminf(x10, x11));
    const float xmax = fmaxf(fmaxf(x00, x01), fmaxf(x10, x11));
    const float ymin = fminf(fminf(y00, y01), fminf(y10, y11));
    const float ymax = fmaxf(fmaxf(y00, y01), fmaxf(y10, y11));

    const int ix0 = (int)floorf(xmin);
    const int ix1 = (int)floorf(xmax) + 1;   // rightmost tap; ix1-ix0 <= 91
    const int iy0 = (int)floorf(ymin);
    const int iy1 = (int)floorf(ymax) + 1;   // bottom tap;   iy1-iy0 <= 91

    const bool empty = (ix1 < 0) || (ix0 > N_IMG - 1) ||
                       (iy1 < 0) || (iy0 > N_IMG - 1);
    const bool interior = (ix0 >= 0) && (ix1 <= N_IMG - 1) &&
                          (iy0 >= 0) && (iy1 <= N_IMG - 1);
    // window: 4-aligned, 96 wide, covers [ix0, ix1] (ix1-win <= 91+3 <= 94)
    const int winl = interior ? min(ix0 & ~3, N_IMG - PIT) : (ix0 & ~3);
    const int nrl  = iy1 - iy0 + 1;          // staged rows <= 92
    const int iy0l = iy0;
    const int fll  = empty ? 1 : (interior ? 2 : 0);

    // ---- per-lane sample-line constants (lane = output column) ----
    const float Xf  = (float)(X0 + lane);
    const float bx  = fmaf(c, Xf, cx);       // x = s*Y + bx
    const float by  = fmaf(-s, Xf, cy);      // y = c*Y + by
    const v2f s2 = {s, s}, c2 = {c, c};
    const v2f bx2 = {bx, bx}, by2 = {by, by};
    const v2f P2 = {(float)PIT, (float)PIT};
    float acc = 0.0f;

    for (int j = 0; j < JOBS; ++j) {
        const int win   = __shfl(winl, j);
        const int iyj   = __shfl(iy0l, j);
        const int nrows = __shfl(nrl,  j);
        const int fl    = __shfl(fll,  j);
        if (fl == 1) continue;               // block-uniform: skip empty job

        if (fl & 2) {
            // interior: ONE contiguous region copy (pitch == staged width)
            const int D = nrows * PIT;
            for (int o = wv * 256; o < D; o += NWAVES * 256) {
                const int d = o + 4 * lane;
                const int r = (unsigned)d / 96u;
                const int cc = d - r * 96;
                const int gr = min(iyj + r, N_IMG - 1);   // tail overshoot clamp
                gload_lds16(src + (size_t)gr * N_IMG + win + cc, buf + o);
            }
        } else {
            // border: masked per-lane DMA; off-image words -> ds_write 0
            for (int r = wv; r < nrows; r += NWAVES) {
                const int gy = iyj + r;
                const bool rok = ((unsigned)gy < (unsigned)N_IMG);
                const float* gp = src + (size_t)gy * N_IMG;
                float* l = buf + r * PIT;
                const int gx = win + lane;
                if (rok && (unsigned)gx < (unsigned)N_IMG) gload_lds4(gp + gx, l);
                else l[lane] = 0.0f;
                if (lane < 32) {
                    const int gx2 = gx + 64;
                    if (rok && (unsigned)gx2 < (unsigned)N_IMG) gload_lds4(gp + gx2, l + 64);
                    else l[64 + lane] = 0.0f;
                }
            }
        }
        __syncthreads();     // drains this block's DMA; staging visible

        // ---- sample 8 dst rows (wave wv -> rows j*64 + wv*8 ..+8) ----
        // driftless exact coords (R5-verified); R8's unrolled pair loop
        __builtin_amdgcn_s_setprio(1);
        const float Yw = (float)(Yq + j * 64 + wv * 8);
        const float basef = -(float)(iyj * PIT + win);
        const v2f b2 = {basef, basef};
        v2f Y2 = {Yw, Yw + 1.0f};
        const v2f two2 = {2.0f, 2.0f};
        v2f acc2 = {0.0f, 0.0f};
        #pragma unroll
        for (int p = 0; p < 4; ++p) {
            const v2f x2 = s2 * Y2 + bx2;    // v_pk_fma (exact chain)
            const v2f y2 = c2 * Y2 + by2;
            const v2f x0f = {floorf(x2.x), floorf(x2.y)};
            const v2f y0f = {floorf(y2.x), floorf(y2.y)};
            const v2f wx = x2 - x0f;
            const v2f wy = y2 - y0f;
            const v2f lif = y0f * P2 + x0f + b2;   // exact (< 2^23)
            const int li0 = (int)lif.x;
            const int li1 = (int)lif.y;
            const v2f t00 = {buf[li0],           buf[li1]};            // ds_read2
            const v2f t01 = {buf[li0 + 1],       buf[li1 + 1]};
            const v2f t10 = {buf[li0 + PIT],     buf[li1 + PIT]};      // ds_read2
            const v2f t11 = {buf[li0 + PIT + 1], buf[li1 + PIT + 1]};
            const v2f top = (t01 - t00) * wx + t00;
            const v2f bot = (t11 - t10) * wx + t10;
            acc2 += (bot - top) * wy + top;
            Y2 += two2;
        }
        acc += acc2.x + acc2.y;
        __builtin_amdgcn_s_setprio(0);

        __syncthreads();     // all waves done reading before next staging
    }

    // ---- block reduce (overlay buf) + atomic merge of 4 y-quarters ----
    buf[wv * 64 + lane] = acc;
    __syncthreads();
    if (wv == 0) {
        float ssum = 0.0f;
        #pragma unroll
        for (int w = 0; w < NWAVES; ++w) ssum += buf[w * 64 + lane];
        atomicAdd(&out[(size_t)(X0 + lane) * N_VIEWS + a], ssum);
    }
}

extern "C" void kernel_launch(void* const* d_in, const int* in_sizes, int n_in,
                              void* d_out, int out_size, void* d_ws, size_t ws_size,
                              hipStream_t stream) {
    const float* img   = (const float*)d_in[0];   // [1024, 1024] f32
    const float* theta = (const float*)d_in[1];   // [90] f32 degrees
    float* out = (float*)d_out;                   // [1024, 90] f32

    const size_t tBytes = (size_t)N_IMG * N_IMG * sizeof(float);   // 4 MB
    float* T   = (float*)d_ws;                    // transposed-flip copy
    float* prm = (float*)((char*)d_ws + tBytes);  // 90 x 8 floats = 2.9 KB
    const int useT = (ws_size >= tBytes + 4096) ? 1 : 0;

    (void)hipMemsetAsync(d_out, 0, (size_t)out_size * sizeof(float), stream);
    if (useT)
        prep<<<dim3(257), 256, 0, stream>>>(img, T, theta, prm);
    radon_fused<<<dim3(16, 4, N_VIEWS), NTHREADS, 0, stream>>>(img, useT ? T : img,
                                                               theta, prm, out, useT);
}